// Round 2
// baseline (385469.531 us; speedup 1.0000x reference)
//
#include <hip/hip_runtime.h>
#include <math.h>

// Problem dims
#define TT 2048
#define VV 1024
#define HH 2048
#define SS (VV + HH)        // 3072: row stride of Wf_w / Wb_w
#define NDW 512             // workgroups per direction
#define UPW (HH / NDW)      // 4 hidden units per wg
#define KSL 16              // k-slices per gate row
#define KPT (HH / KSL)      // 128 k-elements per thread

static_assert(NDW * UPW == HH, "unit coverage");
static_assert(KSL * KPT == HH, "k coverage");

__device__ __forceinline__ float sigmoidf_(float x) {
    return 1.0f / (1.0f + __expf(-x));
}

// Persistent bidirectional LSTM kernel.
// grid = 2*NDW wgs of 256 threads; wg<NDW: forward, else backward.
// Per wg: 4 hidden units; wave w = gate index (i,f,g,o); within wave:
// lane = (unit_local<<4) | k_slice. Each thread owns a 128-long fp32 dot.
__global__ __launch_bounds__(256, 4)
void lstm_kernel(const float* __restrict__ Wf, const float* __restrict__ bfv,
                 const float* __restrict__ Wb, const float* __restrict__ bbv,
                 const int* __restrict__ cidx,
                 float* __restrict__ hsf, float* __restrict__ hsb,
                 unsigned* __restrict__ bar)
{
    const int wg   = blockIdx.x;
    const int dir  = wg >> 9;            // 0 fwd, 1 bwd
    const int w    = wg & (NDW - 1);
    const int tid  = threadIdx.x;
    const int lane = tid & 63;
    const int gate = tid >> 6;           // wave index == gate index
    const int ul   = lane >> 4;          // unit local 0..3
    const int ks   = lane & (KSL - 1);   // k-slice 0..15
    const int unit = w * UPW + ul;
    const int row  = gate * HH + unit;   // gate row in [0,8192)
    const int k0   = ks * KPT;

    const float* W    = dir ? Wb : Wf;
    const float* bias = dir ? bbv : bfv;
    float* hs         = dir ? hsb : hsf;
    unsigned* cnt     = bar + (dir ? 32 : 0);   // separate cachelines

    const float brow = bias[row];
    const float* wrow = W + (size_t)row * SS + VV + k0;  // recurrent slice, 64B-aligned

    // h tile with pad to break the ks*512B bank alias (16-way -> ~2-way)
    __shared__ float hlds[HH + (HH >> 6)];
    __shared__ float glds[4][UPW];
    __shared__ float cst[UPW];
    if (tid < UPW) cst[tid] = 0.0f;

    for (int s = 0; s < TT; ++s) {
        const int t = dir ? (TT - 1 - s) : s;

        // ---- stage h_prev into LDS (each thread: 8 floats, one 64-block) ----
        {
            const int k = tid * 8;
            const int p = k + (k >> 6);
            if (s == 0) {
                const float4 z = make_float4(0.f, 0.f, 0.f, 0.f);
                *reinterpret_cast<float4*>(&hlds[p])     = z;
                *reinterpret_cast<float4*>(&hlds[p + 4]) = z;
            } else {
                const int tprev = dir ? (t + 1) : (t - 1);
                const float* hsrc = hs + (size_t)tprev * HH + k;
                *reinterpret_cast<float4*>(&hlds[p])     = *reinterpret_cast<const float4*>(hsrc);
                *reinterpret_cast<float4*>(&hlds[p + 4]) = *reinterpret_cast<const float4*>(hsrc + 4);
            }
        }
        __syncthreads();

        // ---- recurrent dot: 128 MACs, 64B-line-exact weight loads ----
        float acc = 0.0f;
        #pragma unroll 2
        for (int i = 0; i < KPT / 16; ++i) {          // 8 super-iters x 16 floats
            const float* wp = wrow + i * 16;
            const float4 w0 = *reinterpret_cast<const float4*>(wp);
            const float4 w1 = *reinterpret_cast<const float4*>(wp + 4);
            const float4 w2 = *reinterpret_cast<const float4*>(wp + 8);
            const float4 w3 = *reinterpret_cast<const float4*>(wp + 12);
            const int k = k0 + i * 16;
            const int p = k + (k >> 6);               // constant pad within 16-chunk
            const float4 h0 = *reinterpret_cast<const float4*>(&hlds[p]);
            const float4 h1 = *reinterpret_cast<const float4*>(&hlds[p + 4]);
            const float4 h2 = *reinterpret_cast<const float4*>(&hlds[p + 8]);
            const float4 h3 = *reinterpret_cast<const float4*>(&hlds[p + 12]);
            acc = fmaf(w0.x, h0.x, acc); acc = fmaf(w0.y, h0.y, acc);
            acc = fmaf(w0.z, h0.z, acc); acc = fmaf(w0.w, h0.w, acc);
            acc = fmaf(w1.x, h1.x, acc); acc = fmaf(w1.y, h1.y, acc);
            acc = fmaf(w1.z, h1.z, acc); acc = fmaf(w1.w, h1.w, acc);
            acc = fmaf(w2.x, h2.x, acc); acc = fmaf(w2.y, h2.y, acc);
            acc = fmaf(w2.z, h2.z, acc); acc = fmaf(w2.w, h2.w, acc);
            acc = fmaf(w3.x, h3.x, acc); acc = fmaf(w3.y, h3.y, acc);
            acc = fmaf(w3.z, h3.z, acc); acc = fmaf(w3.w, h3.w, acc);
        }
        #pragma unroll
        for (int off = 1; off < KSL; off <<= 1) acc += __shfl_xor(acc, off, 64);

        if (ks == 0) {
            // one-hot input projection = column gather, exact fp32
            const int xt = cidx[t];
            glds[gate][ul] = acc + W[(size_t)row * SS + xt] + brow;
        }
        __syncthreads();

        // ---- pointwise LSTM cell (4 units) ----
        if (tid < UPW) {
            const float gi = sigmoidf_(glds[0][tid]);
            const float gf = sigmoidf_(glds[1][tid]);
            const float gg = tanhf(glds[2][tid]);
            const float go = sigmoidf_(glds[3][tid]);
            const float c  = gf * cst[tid] + gi * gg;
            cst[tid] = c;
            hs[(size_t)t * HH + w * UPW + tid] = go * tanhf(c);
        }

        // ---- grid barrier for this direction (monotonic counter) ----
        __builtin_amdgcn_fence(__ATOMIC_RELEASE, "agent");
        __syncthreads();
        if (tid == 0) {
            __hip_atomic_fetch_add(cnt, 1u, __ATOMIC_RELAXED, __HIP_MEMORY_SCOPE_AGENT);
            const unsigned tgt = (unsigned)(s + 1) * NDW;
            while (__hip_atomic_load(cnt, __ATOMIC_RELAXED, __HIP_MEMORY_SCOPE_AGENT) < tgt) {
                __builtin_amdgcn_s_sleep(2);
            }
        }
        __syncthreads();
        __builtin_amdgcn_fence(__ATOMIC_ACQUIRE, "agent");
    }
}

// out[t,v] = sum_j merged[t,j]*Wo[v,j] + bo[v],  merged = [hf | hb], K = 4096.
// 64x64 tile, BK=32, 256 threads, 4x4 per thread, fp32.
__global__ __launch_bounds__(256)
void out_gemm(const float* __restrict__ hsf, const float* __restrict__ hsb,
              const float* __restrict__ Wo, const float* __restrict__ bo,
              float* __restrict__ out)
{
    const int bn = blockIdx.x;           // v tile (16)
    const int bm = blockIdx.y;           // t tile (32)
    const int tid = threadIdx.x;
    const int tx = tid & 15, ty = tid >> 4;
    const int t0 = bm * 64, v0 = bn * 64;

    __shared__ float As[32][72];
    __shared__ float Bs[32][72];

    float acc[4][4] = {};

    const int rr = tid >> 2;             // 0..63
    const int kc = tid & 3;              // 0..3 (8 k's each)

    for (int kb = 0; kb < 2 * HH; kb += 32) {
        {
            const int k = kb + kc * 8;
            const float* asrc = (k < HH) ? (hsf + (size_t)(t0 + rr) * HH + k)
                                         : (hsb + (size_t)(t0 + rr) * HH + (k - HH));
            const float4 a0 = *reinterpret_cast<const float4*>(asrc);
            const float4 a1 = *reinterpret_cast<const float4*>(asrc + 4);
            const int kk = kc * 8;
            As[kk+0][rr]=a0.x; As[kk+1][rr]=a0.y; As[kk+2][rr]=a0.z; As[kk+3][rr]=a0.w;
            As[kk+4][rr]=a1.x; As[kk+5][rr]=a1.y; As[kk+6][rr]=a1.z; As[kk+7][rr]=a1.w;
            const float* bsrc = Wo + (size_t)(v0 + rr) * (2 * HH) + k;
            const float4 b0 = *reinterpret_cast<const float4*>(bsrc);
            const float4 b1 = *reinterpret_cast<const float4*>(bsrc + 4);
            Bs[kk+0][rr]=b0.x; Bs[kk+1][rr]=b0.y; Bs[kk+2][rr]=b0.z; Bs[kk+3][rr]=b0.w;
            Bs[kk+4][rr]=b1.x; Bs[kk+5][rr]=b1.y; Bs[kk+6][rr]=b1.z; Bs[kk+7][rr]=b1.w;
        }
        __syncthreads();
        #pragma unroll 8
        for (int kk = 0; kk < 32; ++kk) {
            const float4 av = *reinterpret_cast<const float4*>(&As[kk][ty * 4]);
            const float4 bv = *reinterpret_cast<const float4*>(&Bs[kk][tx * 4]);
            const float a[4] = {av.x, av.y, av.z, av.w};
            const float b[4] = {bv.x, bv.y, bv.z, bv.w};
            #pragma unroll
            for (int i2 = 0; i2 < 4; ++i2)
                #pragma unroll
                for (int j2 = 0; j2 < 4; ++j2)
                    acc[i2][j2] = fmaf(a[i2], b[j2], acc[i2][j2]);
        }
        __syncthreads();
    }
    #pragma unroll
    for (int i2 = 0; i2 < 4; ++i2) {
        const int t = t0 + ty * 4 + i2;
        #pragma unroll
        for (int j2 = 0; j2 < 4; ++j2) {
            const int v = v0 + tx * 4 + j2;
            out[(size_t)t * VV + v] = acc[i2][j2] + bo[v];
        }
    }
}

extern "C" void kernel_launch(void* const* d_in, const int* in_sizes, int n_in,
                              void* d_out, int out_size, void* d_ws, size_t ws_size,
                              hipStream_t stream)
{
    (void)in_sizes; (void)n_in; (void)out_size; (void)ws_size;

    const float* Wf  = (const float*)d_in[0];
    const float* bfv = (const float*)d_in[1];
    const float* Wb  = (const float*)d_in[2];
    const float* bbv = (const float*)d_in[3];
    const float* Wo  = (const float*)d_in[4];
    const float* bo  = (const float*)d_in[5];
    const int*   cid = (const int*)d_in[6];
    float* out = (float*)d_out;

    unsigned char* ws = (unsigned char*)d_ws;
    unsigned* bar = (unsigned*)ws;                         // 256 B barrier area
    float* hsf = (float*)(ws + 256);                       // [T][H] fp32, 16 MiB
    float* hsb = hsf + (size_t)TT * HH;                    // [T][H] fp32, 16 MiB

    // Re-zero barrier counters every launch (ws is poisoned once, never restored)
    (void)hipMemsetAsync(bar, 0, 256, stream);

    lstm_kernel<<<dim3(2 * NDW), dim3(256), 0, stream>>>(Wf, bfv, Wb, bbv, cid,
                                                         hsf, hsb, bar);
    out_gemm<<<dim3(VV / 64, TT / 64), dim3(256), 0, stream>>>(hsf, hsb, Wo, bo, out);
}

// Round 3
// 221382.349 us; speedup vs baseline: 1.7412x; 1.7412x over previous
//
#include <hip/hip_runtime.h>
#include <math.h>

// Problem dims
#define TT 2048
#define VV 1024
#define HH 2048
#define SS (VV + HH)        // 3072: row stride of Wf_w / Wb_w

// LSTM kernel geometry: 256 WGs x 1024 threads, one WG per CU.
#define NWGD 128            // workgroups per direction
#define BTH  1024           // threads per workgroup (16 waves)
#define UPW  (HH / NWGD)    // 16 hidden units per wg
#define ROWS (4 * UPW)      // 64 gate-rows per wg
#define KSL  16             // k-slices per gate row
#define KPT  (HH / KSL)     // 128 k-elements per thread

static_assert(NWGD * UPW == HH, "unit coverage");
static_assert(ROWS * KSL == BTH, "thread coverage");
static_assert(KSL * KPT == HH, "k coverage");

// Barrier area layout (uints), per direction at bar + dir*2048:
//   leaf l (l<8):   +l*64        (256B stride; 16 WGs per leaf)
//   root:           +8*64
//   flag f (f<8):   +(9+f)*64
#define BAR_UINTS_PER_DIR 2048

__device__ __forceinline__ float sigmoidf_(float x) {
    return 1.0f / (1.0f + __expf(-x));
}

__global__ __launch_bounds__(BTH, 4)
void lstm_kernel(const float* __restrict__ Wf, const float* __restrict__ bfv,
                 const float* __restrict__ Wb, const float* __restrict__ bbv,
                 const int* __restrict__ cidx,
                 float* __restrict__ hsf, float* __restrict__ hsb,
                 unsigned* __restrict__ bar)
{
    const int wg   = blockIdx.x;
    const int dir  = wg >> 7;            // 0 fwd, 1 bwd
    const int w    = wg & (NWGD - 1);
    const int tid  = threadIdx.x;
    const int r    = tid >> 4;           // local gate-row 0..63
    const int ks   = tid & (KSL - 1);    // k-slice 0..15
    const int g    = r >> 4;             // gate 0..3
    const int ul   = r & (UPW - 1);      // unit local 0..15
    const int unit = w * UPW + ul;
    const int row  = g * HH + unit;      // gate row in [0,8192)
    const int k0   = ks * KPT;

    const float* W    = dir ? Wb : Wf;
    const float* bias = dir ? bbv : bfv;
    float* hs         = dir ? hsb : hsf;
    unsigned* base    = bar + dir * BAR_UINTS_PER_DIR;

    const float brow = bias[row];
    const float* wrow = W + (size_t)row * SS + VV + k0;  // recurrent slice, 64B-aligned

    // h tile with pad to break the ks*512B bank alias
    __shared__ float hlds[HH + (HH >> 6)];
    __shared__ float glds[4][UPW];
    __shared__ float cst[UPW];
    // Force 1 WG/CU so 256 WGs are guaranteed co-resident across 256 CUs
    // (required for the grid barrier): 80KB pad -> only one 89KB WG fits in 160KB.
    __shared__ char force_one_wg[80 * 1024];
    if (tid == 0) ((volatile char*)force_one_wg)[0] = 0;   // keep alive

    if (tid < UPW) cst[tid] = 0.0f;

    for (int s = 0; s < TT; ++s) {
        const int t = dir ? (TT - 1 - s) : s;

        // ---- stage h_prev into LDS (each thread: 2 floats) ----
        {
            const int k = tid * 2;
            const int p = k + (k >> 6);
            if (s == 0) {
                hlds[p]     = 0.0f;
                hlds[p + 1] = 0.0f;
            } else {
                const int tprev = dir ? (t + 1) : (t - 1);
                const float2 hv = *reinterpret_cast<const float2*>(hs + (size_t)tprev * HH + k);
                hlds[p]     = hv.x;
                hlds[p + 1] = hv.y;
            }
        }
        __syncthreads();

        // ---- recurrent dot: 128 MACs, 64B-line-exact weight loads ----
        float acc = 0.0f;
        #pragma unroll 2
        for (int i = 0; i < KPT / 16; ++i) {          // 8 super-iters x 16 floats
            const float* wp = wrow + i * 16;
            const float4 w0 = *reinterpret_cast<const float4*>(wp);
            const float4 w1 = *reinterpret_cast<const float4*>(wp + 4);
            const float4 w2 = *reinterpret_cast<const float4*>(wp + 8);
            const float4 w3 = *reinterpret_cast<const float4*>(wp + 12);
            const int k = k0 + i * 16;
            const int p = k + (k >> 6);               // constant pad within 16-chunk
            const float4 h0 = *reinterpret_cast<const float4*>(&hlds[p]);
            const float4 h1 = *reinterpret_cast<const float4*>(&hlds[p + 4]);
            const float4 h2 = *reinterpret_cast<const float4*>(&hlds[p + 8]);
            const float4 h3 = *reinterpret_cast<const float4*>(&hlds[p + 12]);
            acc = fmaf(w0.x, h0.x, acc); acc = fmaf(w0.y, h0.y, acc);
            acc = fmaf(w0.z, h0.z, acc); acc = fmaf(w0.w, h0.w, acc);
            acc = fmaf(w1.x, h1.x, acc); acc = fmaf(w1.y, h1.y, acc);
            acc = fmaf(w1.z, h1.z, acc); acc = fmaf(w1.w, h1.w, acc);
            acc = fmaf(w2.x, h2.x, acc); acc = fmaf(w2.y, h2.y, acc);
            acc = fmaf(w2.z, h2.z, acc); acc = fmaf(w2.w, h2.w, acc);
            acc = fmaf(w3.x, h3.x, acc); acc = fmaf(w3.y, h3.y, acc);
            acc = fmaf(w3.z, h3.z, acc); acc = fmaf(w3.w, h3.w, acc);
        }
        #pragma unroll
        for (int off = 1; off < KSL; off <<= 1) acc += __shfl_xor(acc, off, 64);

        if (ks == 0) {
            // one-hot input projection = column gather, exact fp32
            const int xt = cidx[t];
            glds[g][ul] = acc + W[(size_t)row * SS + xt] + brow;
        }
        __syncthreads();

        // ---- pointwise LSTM cell (16 units) ----
        if (tid < UPW) {
            const float gi = sigmoidf_(glds[0][tid]);
            const float gf = sigmoidf_(glds[1][tid]);
            const float gg = tanhf(glds[2][tid]);
            const float go = sigmoidf_(glds[3][tid]);
            const float c  = gf * cst[tid] + gi * gg;
            cst[tid] = c;
            hs[(size_t)t * HH + w * UPW + tid] = go * tanhf(c);
        }

        // ---- grid barrier for this direction: tree counters + replicated flags ----
        __builtin_amdgcn_fence(__ATOMIC_RELEASE, "agent");
        __syncthreads();
        if (tid == 0) {
            unsigned* leaf = base + (w >> 4) * 64;
            const unsigned lo = __hip_atomic_fetch_add(leaf, 1u, __ATOMIC_ACQ_REL,
                                                       __HIP_MEMORY_SCOPE_AGENT);
            if (lo + 1 == 16u * (unsigned)(s + 1)) {
                unsigned* root = base + 8 * 64;
                const unsigned ro = __hip_atomic_fetch_add(root, 1u, __ATOMIC_ACQ_REL,
                                                           __HIP_MEMORY_SCOPE_AGENT);
                if (ro + 1 == 8u * (unsigned)(s + 1)) {
                    #pragma unroll
                    for (int f = 0; f < 8; ++f)
                        __hip_atomic_store(base + (9 + f) * 64, (unsigned)(s + 1),
                                           __ATOMIC_RELEASE, __HIP_MEMORY_SCOPE_AGENT);
                }
            }
            unsigned* fl = base + (9 + (w & 7)) * 64;
            while (__hip_atomic_load(fl, __ATOMIC_ACQUIRE, __HIP_MEMORY_SCOPE_AGENT)
                   < (unsigned)(s + 1)) {
                __builtin_amdgcn_s_sleep(2);
            }
        }
        __syncthreads();
        __builtin_amdgcn_fence(__ATOMIC_ACQUIRE, "agent");
    }
}

// out[t,v] = sum_j merged[t,j]*Wo[v,j] + bo[v],  merged = [hf | hb], K = 4096.
// 64x64 tile, BK=32, 256 threads, 4x4 per thread, fp32.
__global__ __launch_bounds__(256)
void out_gemm(const float* __restrict__ hsf, const float* __restrict__ hsb,
              const float* __restrict__ Wo, const float* __restrict__ bo,
              float* __restrict__ out)
{
    const int bn = blockIdx.x;           // v tile (16)
    const int bm = blockIdx.y;           // t tile (32)
    const int tid = threadIdx.x;
    const int tx = tid & 15, ty = tid >> 4;
    const int t0 = bm * 64, v0 = bn * 64;

    __shared__ float As[32][72];
    __shared__ float Bs[32][72];

    float acc[4][4] = {};

    const int rr = tid >> 2;             // 0..63
    const int kc = tid & 3;              // 0..3 (8 k's each)

    for (int kb = 0; kb < 2 * HH; kb += 32) {
        {
            const int k = kb + kc * 8;
            const float* asrc = (k < HH) ? (hsf + (size_t)(t0 + rr) * HH + k)
                                         : (hsb + (size_t)(t0 + rr) * HH + (k - HH));
            const float4 a0 = *reinterpret_cast<const float4*>(asrc);
            const float4 a1 = *reinterpret_cast<const float4*>(asrc + 4);
            const int kk = kc * 8;
            As[kk+0][rr]=a0.x; As[kk+1][rr]=a0.y; As[kk+2][rr]=a0.z; As[kk+3][rr]=a0.w;
            As[kk+4][rr]=a1.x; As[kk+5][rr]=a1.y; As[kk+6][rr]=a1.z; As[kk+7][rr]=a1.w;
            const float* bsrc = Wo + (size_t)(v0 + rr) * (2 * HH) + k;
            const float4 b0 = *reinterpret_cast<const float4*>(bsrc);
            const float4 b1 = *reinterpret_cast<const float4*>(bsrc + 4);
            Bs[kk+0][rr]=b0.x; Bs[kk+1][rr]=b0.y; Bs[kk+2][rr]=b0.z; Bs[kk+3][rr]=b0.w;
            Bs[kk+4][rr]=b1.x; Bs[kk+5][rr]=b1.y; Bs[kk+6][rr]=b1.z; Bs[kk+7][rr]=b1.w;
        }
        __syncthreads();
        #pragma unroll 8
        for (int kk = 0; kk < 32; ++kk) {
            const float4 av = *reinterpret_cast<const float4*>(&As[kk][ty * 4]);
            const float4 bv = *reinterpret_cast<const float4*>(&Bs[kk][tx * 4]);
            const float a[4] = {av.x, av.y, av.z, av.w};
            const float b[4] = {bv.x, bv.y, bv.z, bv.w};
            #pragma unroll
            for (int i2 = 0; i2 < 4; ++i2)
                #pragma unroll
                for (int j2 = 0; j2 < 4; ++j2)
                    acc[i2][j2] = fmaf(a[i2], b[j2], acc[i2][j2]);
        }
        __syncthreads();
    }
    #pragma unroll
    for (int i2 = 0; i2 < 4; ++i2) {
        const int t = t0 + ty * 4 + i2;
        #pragma unroll
        for (int j2 = 0; j2 < 4; ++j2) {
            const int v = v0 + tx * 4 + j2;
            out[(size_t)t * VV + v] = acc[i2][j2] + bo[v];
        }
    }
}

extern "C" void kernel_launch(void* const* d_in, const int* in_sizes, int n_in,
                              void* d_out, int out_size, void* d_ws, size_t ws_size,
                              hipStream_t stream)
{
    (void)in_sizes; (void)n_in; (void)out_size; (void)ws_size;

    const float* Wf  = (const float*)d_in[0];
    const float* bfv = (const float*)d_in[1];
    const float* Wb  = (const float*)d_in[2];
    const float* bbv = (const float*)d_in[3];
    const float* Wo  = (const float*)d_in[4];
    const float* bo  = (const float*)d_in[5];
    const int*   cid = (const int*)d_in[6];
    float* out = (float*)d_out;

    unsigned char* ws = (unsigned char*)d_ws;
    unsigned* bar = (unsigned*)ws;                         // 16 KiB barrier area
    float* hsf = (float*)(ws + 65536);                     // [T][H] fp32, 16 MiB
    float* hsb = hsf + (size_t)TT * HH;                    // [T][H] fp32, 16 MiB

    // Re-zero barrier counters every launch (ws is poisoned once, never restored)
    (void)hipMemsetAsync(bar, 0, 16384, stream);

    lstm_kernel<<<dim3(2 * NWGD), dim3(BTH), 0, stream>>>(Wf, bfv, Wb, bbv, cid,
                                                          hsf, hsb, bar);
    out_gemm<<<dim3(VV / 64, TT / 64), dim3(256), 0, stream>>>(hsf, hsb, Wo, bo, out);
}

// Round 4
// 47178.592 us; speedup vs baseline: 8.1704x; 4.6924x over previous
//
#include <hip/hip_runtime.h>
#include <math.h>

// Problem dims
#define TT 2048
#define VV 1024
#define HH 2048
#define SS (VV + HH)        // 3072: row stride of Wf_w / Wb_w

// LSTM kernel geometry: 256 WGs x 1024 threads, one WG per CU.
#define NWGD 128            // workgroups per direction
#define BTH  1024           // threads per workgroup (16 waves)
#define UPW  (HH / NWGD)    // 16 hidden units per wg
#define ROWS (4 * UPW)      // 64 gate-rows per wg
#define KSL  16             // k-slices per gate row
#define KPT  (HH / KSL)     // 128 k-elements per thread

static_assert(NWGD * UPW == HH, "unit coverage");
static_assert(ROWS * KSL == BTH, "thread coverage");
static_assert(KSL * KPT == HH, "k coverage");

// Barrier area layout (uints), per direction at bar + dir*2048:
//   leaf l (l<8):   +l*64        (256B stride; 16 WGs per leaf)
//   root:           +8*64
//   flag f (f<8):   +(9+f)*64
#define BAR_UINTS_PER_DIR 2048

__device__ __forceinline__ float sigmoidf_(float x) {
    return 1.0f / (1.0f + __expf(-x));
}

__global__ __launch_bounds__(BTH, 4)
void lstm_kernel(const float* __restrict__ Wf, const float* __restrict__ bfv,
                 const float* __restrict__ Wb, const float* __restrict__ bbv,
                 const int* __restrict__ cidx,
                 float* __restrict__ hsf, float* __restrict__ hsb,
                 unsigned* __restrict__ bar)
{
    const int wg   = blockIdx.x;
    const int dir  = wg >> 7;            // 0 fwd, 1 bwd
    const int w    = wg & (NWGD - 1);
    const int tid  = threadIdx.x;
    const int r    = tid >> 4;           // local gate-row 0..63
    const int ks   = tid & (KSL - 1);    // k-slice 0..15
    const int g    = r >> 4;             // gate 0..3
    const int ul   = r & (UPW - 1);      // unit local 0..15
    const int unit = w * UPW + ul;
    const int row  = g * HH + unit;      // gate row in [0,8192)
    const int k0   = ks * KPT;

    const float* W    = dir ? Wb : Wf;
    const float* bias = dir ? bbv : bfv;
    float* hs         = dir ? hsb : hsf;
    unsigned* base    = bar + dir * BAR_UINTS_PER_DIR;

    const float brow = bias[row];
    const float* wrow = W + (size_t)row * SS + VV + k0;  // recurrent slice, 64B-aligned

    // h tile with pad to break the ks*512B bank alias
    __shared__ float hlds[HH + (HH >> 6)];
    __shared__ float glds[4][UPW];
    __shared__ float cst[UPW];
    // Force 1 WG/CU so 256 WGs are guaranteed co-resident across 256 CUs
    // (required for the grid barrier): 80KB pad -> only one 89KB WG fits in 160KB.
    __shared__ char force_one_wg[80 * 1024];
    if (tid == 0) ((volatile char*)force_one_wg)[0] = 0;   // keep alive

    if (tid < UPW) cst[tid] = 0.0f;

    for (int s = 0; s < TT; ++s) {
        const int t = dir ? (TT - 1 - s) : s;

        // ---- stage h_prev into LDS via agent-coherent (sc-flagged) loads ----
        // No acquire fence anywhere: coherence is carried by the accesses
        // themselves (relaxed agent atomics bypass stale L1/L2), so the
        // weight working set is never invalidated out of L2/L3.
        {
            const int k = tid * 2;
            const int p = k + (k >> 6);
            if (s == 0) {
                hlds[p]     = 0.0f;
                hlds[p + 1] = 0.0f;
            } else {
                const int tprev = dir ? (t + 1) : (t - 1);
                const float* hsrc = hs + (size_t)tprev * HH + k;
                hlds[p]     = __hip_atomic_load(hsrc,     __ATOMIC_RELAXED, __HIP_MEMORY_SCOPE_AGENT);
                hlds[p + 1] = __hip_atomic_load(hsrc + 1, __ATOMIC_RELAXED, __HIP_MEMORY_SCOPE_AGENT);
            }
        }
        __syncthreads();

        // ---- recurrent dot: 128 MACs, 64B-line-exact weight loads ----
        float acc = 0.0f;
        #pragma unroll 2
        for (int i = 0; i < KPT / 16; ++i) {          // 8 super-iters x 16 floats
            const float* wp = wrow + i * 16;
            const float4 w0 = *reinterpret_cast<const float4*>(wp);
            const float4 w1 = *reinterpret_cast<const float4*>(wp + 4);
            const float4 w2 = *reinterpret_cast<const float4*>(wp + 8);
            const float4 w3 = *reinterpret_cast<const float4*>(wp + 12);
            const int k = k0 + i * 16;
            const int p = k + (k >> 6);               // constant pad within 16-chunk
            const float4 h0 = *reinterpret_cast<const float4*>(&hlds[p]);
            const float4 h1 = *reinterpret_cast<const float4*>(&hlds[p + 4]);
            const float4 h2 = *reinterpret_cast<const float4*>(&hlds[p + 8]);
            const float4 h3 = *reinterpret_cast<const float4*>(&hlds[p + 12]);
            acc = fmaf(w0.x, h0.x, acc); acc = fmaf(w0.y, h0.y, acc);
            acc = fmaf(w0.z, h0.z, acc); acc = fmaf(w0.w, h0.w, acc);
            acc = fmaf(w1.x, h1.x, acc); acc = fmaf(w1.y, h1.y, acc);
            acc = fmaf(w1.z, h1.z, acc); acc = fmaf(w1.w, h1.w, acc);
            acc = fmaf(w2.x, h2.x, acc); acc = fmaf(w2.y, h2.y, acc);
            acc = fmaf(w2.z, h2.z, acc); acc = fmaf(w2.w, h2.w, acc);
            acc = fmaf(w3.x, h3.x, acc); acc = fmaf(w3.y, h3.y, acc);
            acc = fmaf(w3.z, h3.z, acc); acc = fmaf(w3.w, h3.w, acc);
        }
        #pragma unroll
        for (int off = 1; off < KSL; off <<= 1) acc += __shfl_xor(acc, off, 64);

        if (ks == 0) {
            // one-hot input projection = column gather, exact fp32
            const int xt = cidx[t];
            glds[g][ul] = acc + W[(size_t)row * SS + xt] + brow;
        }
        __syncthreads();

        // ---- pointwise LSTM cell (16 units; all in wave 0) ----
        if (tid < UPW) {
            const float gi = sigmoidf_(glds[0][tid]);
            const float gf = sigmoidf_(glds[1][tid]);
            const float gg = tanhf(glds[2][tid]);
            const float go = sigmoidf_(glds[3][tid]);
            const float c  = gf * cst[tid] + gi * gg;
            cst[tid] = c;
            const float hv = go * tanhf(c);
            // agent-coherent write-through store: visible at the shared point
            // once vmcnt drains; no cache-flush fence needed.
            __hip_atomic_store(hs + (size_t)t * HH + w * UPW + tid, hv,
                               __ATOMIC_RELAXED, __HIP_MEMORY_SCOPE_AGENT);
        }
        __syncthreads();

        // ---- grid barrier: tree counters + replicated flags, all RELAXED ----
        if (tid == 0) {
            // h stores above were issued by tids 0..15 == wave 0 (this wave):
            // drain this wave's outstanding stores to the coherence point.
            asm volatile("s_waitcnt vmcnt(0)" ::: "memory");
            unsigned* leaf = base + (w >> 4) * 64;
            const unsigned lo = __hip_atomic_fetch_add(leaf, 1u, __ATOMIC_RELAXED,
                                                       __HIP_MEMORY_SCOPE_AGENT);
            if (lo + 1 == 16u * (unsigned)(s + 1)) {
                unsigned* root = base + 8 * 64;
                const unsigned ro = __hip_atomic_fetch_add(root, 1u, __ATOMIC_RELAXED,
                                                           __HIP_MEMORY_SCOPE_AGENT);
                if (ro + 1 == 8u * (unsigned)(s + 1)) {
                    #pragma unroll
                    for (int f = 0; f < 8; ++f)
                        __hip_atomic_store(base + (9 + f) * 64, (unsigned)(s + 1),
                                           __ATOMIC_RELAXED, __HIP_MEMORY_SCOPE_AGENT);
                }
            }
            unsigned* fl = base + (9 + (w & 7)) * 64;
            while (__hip_atomic_load(fl, __ATOMIC_RELAXED, __HIP_MEMORY_SCOPE_AGENT)
                   < (unsigned)(s + 1)) {
                __builtin_amdgcn_s_sleep(2);
            }
            asm volatile("" ::: "memory");   // compiler barrier: no hoisting past poll
        }
        __syncthreads();
    }
}

// out[t,v] = sum_j merged[t,j]*Wo[v,j] + bo[v],  merged = [hf | hb], K = 4096.
// 64x64 tile, BK=32, 256 threads, 4x4 per thread, fp32.
__global__ __launch_bounds__(256)
void out_gemm(const float* __restrict__ hsf, const float* __restrict__ hsb,
              const float* __restrict__ Wo, const float* __restrict__ bo,
              float* __restrict__ out)
{
    const int bn = blockIdx.x;           // v tile (16)
    const int bm = blockIdx.y;           // t tile (32)
    const int tid = threadIdx.x;
    const int tx = tid & 15, ty = tid >> 4;
    const int t0 = bm * 64, v0 = bn * 64;

    __shared__ float As[32][72];
    __shared__ float Bs[32][72];

    float acc[4][4] = {};

    const int rr = tid >> 2;             // 0..63
    const int kc = tid & 3;              // 0..3 (8 k's each)

    for (int kb = 0; kb < 2 * HH; kb += 32) {
        {
            const int k = kb + kc * 8;
            const float* asrc = (k < HH) ? (hsf + (size_t)(t0 + rr) * HH + k)
                                         : (hsb + (size_t)(t0 + rr) * HH + (k - HH));
            const float4 a0 = *reinterpret_cast<const float4*>(asrc);
            const float4 a1 = *reinterpret_cast<const float4*>(asrc + 4);
            const int kk = kc * 8;
            As[kk+0][rr]=a0.x; As[kk+1][rr]=a0.y; As[kk+2][rr]=a0.z; As[kk+3][rr]=a0.w;
            As[kk+4][rr]=a1.x; As[kk+5][rr]=a1.y; As[kk+6][rr]=a1.z; As[kk+7][rr]=a1.w;
            const float* bsrc = Wo + (size_t)(v0 + rr) * (2 * HH) + k;
            const float4 b0 = *reinterpret_cast<const float4*>(bsrc);
            const float4 b1 = *reinterpret_cast<const float4*>(bsrc + 4);
            Bs[kk+0][rr]=b0.x; Bs[kk+1][rr]=b0.y; Bs[kk+2][rr]=b0.z; Bs[kk+3][rr]=b0.w;
            Bs[kk+4][rr]=b1.x; Bs[kk+5][rr]=b1.y; Bs[kk+6][rr]=b1.z; Bs[kk+7][rr]=b1.w;
        }
        __syncthreads();
        #pragma unroll 8
        for (int kk = 0; kk < 32; ++kk) {
            const float4 av = *reinterpret_cast<const float4*>(&As[kk][ty * 4]);
            const float4 bv = *reinterpret_cast<const float4*>(&Bs[kk][tx * 4]);
            const float a[4] = {av.x, av.y, av.z, av.w};
            const float b[4] = {bv.x, bv.y, bv.z, bv.w};
            #pragma unroll
            for (int i2 = 0; i2 < 4; ++i2)
                #pragma unroll
                for (int j2 = 0; j2 < 4; ++j2)
                    acc[i2][j2] = fmaf(a[i2], b[j2], acc[i2][j2]);
        }
        __syncthreads();
    }
    #pragma unroll
    for (int i2 = 0; i2 < 4; ++i2) {
        const int t = t0 + ty * 4 + i2;
        #pragma unroll
        for (int j2 = 0; j2 < 4; ++j2) {
            const int v = v0 + tx * 4 + j2;
            out[(size_t)t * VV + v] = acc[i2][j2] + bo[v];
        }
    }
}

extern "C" void kernel_launch(void* const* d_in, const int* in_sizes, int n_in,
                              void* d_out, int out_size, void* d_ws, size_t ws_size,
                              hipStream_t stream)
{
    (void)in_sizes; (void)n_in; (void)out_size; (void)ws_size;

    const float* Wf  = (const float*)d_in[0];
    const float* bfv = (const float*)d_in[1];
    const float* Wb  = (const float*)d_in[2];
    const float* bbv = (const float*)d_in[3];
    const float* Wo  = (const float*)d_in[4];
    const float* bo  = (const float*)d_in[5];
    const int*   cid = (const int*)d_in[6];
    float* out = (float*)d_out;

    unsigned char* ws = (unsigned char*)d_ws;
    unsigned* bar = (unsigned*)ws;                         // 16 KiB barrier area
    float* hsf = (float*)(ws + 65536);                     // [T][H] fp32, 16 MiB
    float* hsb = hsf + (size_t)TT * HH;                    // [T][H] fp32, 16 MiB

    // Re-zero barrier counters every launch (ws is poisoned once, never restored)
    (void)hipMemsetAsync(bar, 0, 16384, stream);

    lstm_kernel<<<dim3(2 * NWGD), dim3(BTH), 0, stream>>>(Wf, bfv, Wb, bbv, cid,
                                                          hsf, hsb, bar);
    out_gemm<<<dim3(VV / 64, TT / 64), dim3(256), 0, stream>>>(hsf, hsb, Wo, bo, out);
}

// Round 5
// 9142.782 us; speedup vs baseline: 42.1611x; 5.1602x over previous
//
#include <hip/hip_runtime.h>
#include <math.h>

// Problem dims
#define TT 2048
#define VV 1024
#define HH 2048
#define SS (VV + HH)        // 3072: row stride of Wf_w / Wb_w

// Geometry: 256 WGs x 512 threads, one WG per CU (forced by ~156KB LDS).
#define NWGD 128            // workgroups per direction
#define BTH  512            // threads per workgroup (8 waves)
#define UPW  16             // hidden units per wg
#define ROWS 64             // gate rows per wg (4 gates x 16 units)
#define KSL  8              // k-slices per gate row
#define KPT  256            // k-elements per thread
#define NCH  64             // float4 chunks per thread (KPT/4)
#define RCH  46             // chunks resident in VGPRs (184 regs)
#define LCH  (NCH - RCH)    // 18 chunks resident in LDS (147456 B)

static_assert(NWGD * UPW == HH, "unit coverage");
static_assert(ROWS * KSL == BTH, "thread coverage");
static_assert(KSL * KPT == HH, "k coverage");

// Barrier area layout (uints), per direction at bar + dir*2048:
//   leaf l (l<8): +l*64 ; root: +8*64 ; flag f (f<8): +(9+f)*64
#define BAR_UINTS_PER_DIR 2048

__device__ __forceinline__ float sigmoidf_(float x) {
    return 1.0f / (1.0f + __expf(-x));
}

// h LDS index: +4 floats of pad per 256-float block so the 8 distinct
// ks-addresses (stride 1024B) land in 8 distinct bank groups.
#define HIDX(k) ((k) + 4 * ((k) >> 8))

__global__ __launch_bounds__(BTH, 2)
void lstm_kernel(const float* __restrict__ Wf, const float* __restrict__ bfv,
                 const float* __restrict__ Wb, const float* __restrict__ bbv,
                 const int* __restrict__ cidx,
                 float* __restrict__ hsf, float* __restrict__ hsb,
                 unsigned* __restrict__ bar)
{
    const int wg   = blockIdx.x;
    const int dir  = wg >> 7;            // 0 fwd, 1 bwd
    const int w    = wg & (NWGD - 1);
    const int tid  = threadIdx.x;
    const int r    = tid >> 3;           // local gate-row 0..63
    const int ks   = tid & (KSL - 1);    // k-slice 0..7
    const int g    = r >> 4;             // gate 0..3
    const int ul   = r & (UPW - 1);      // unit local 0..15
    const int unit = w * UPW + ul;
    const int row  = g * HH + unit;      // gate row in [0,8192)

    const float* W    = dir ? Wb : Wf;
    const float* bias = dir ? bbv : bfv;
    float* hs         = dir ? hsb : hsf;
    unsigned* base    = bar + dir * BAR_UINTS_PER_DIR;

    const float  brow = bias[row];
    const float* grow = W + (size_t)row * SS;            // for one-hot gather
    const float* wbase = grow + VV + ks * KPT;           // recurrent slice

    __shared__ float hlds[HH + 4 * (HH / 256)];          // 2080 floats
    __shared__ float wlds[LCH * BTH * 4];                // 36864 floats = 144KB
    __shared__ float glds[4][UPW];
    __shared__ float cst[UPW];

    // ---- one-time: load weight slab into VGPRs + LDS ----
    float4 wreg[RCH];
    #pragma unroll
    for (int j = 0; j < RCH; ++j)
        wreg[j] = *reinterpret_cast<const float4*>(wbase + j * 4);
    #pragma unroll
    for (int j = 0; j < LCH; ++j)
        *reinterpret_cast<float4*>(&wlds[(j * BTH + tid) * 4]) =
            *reinterpret_cast<const float4*>(wbase + (RCH + j) * 4);

    if (tid < UPW) cst[tid] = 0.0f;
    __syncthreads();

    for (int s = 0; s < TT; ++s) {
        const int t  = dir ? (TT - 1 - s) : s;
        const int xt = cidx[t];
        // prefetch one-hot gather early (exact fp32, L3-hot after step 1)
        float gxv = 0.0f;
        if (ks == 0) gxv = grow[xt];

        // ---- stage h_prev into LDS via agent-coherent loads (4 floats) ----
        {
            const int k = tid * 4;
            const int p = HIDX(k);
            if (s == 0) {
                *reinterpret_cast<float4*>(&hlds[p]) = make_float4(0.f, 0.f, 0.f, 0.f);
            } else {
                const int tprev = dir ? (t + 1) : (t - 1);
                const float* hsrc = hs + (size_t)tprev * HH + k;
                float4 hv;
                hv.x = __hip_atomic_load(hsrc,     __ATOMIC_RELAXED, __HIP_MEMORY_SCOPE_AGENT);
                hv.y = __hip_atomic_load(hsrc + 1, __ATOMIC_RELAXED, __HIP_MEMORY_SCOPE_AGENT);
                hv.z = __hip_atomic_load(hsrc + 2, __ATOMIC_RELAXED, __HIP_MEMORY_SCOPE_AGENT);
                hv.w = __hip_atomic_load(hsrc + 3, __ATOMIC_RELAXED, __HIP_MEMORY_SCOPE_AGENT);
                *reinterpret_cast<float4*>(&hlds[p]) = hv;
            }
        }
        __syncthreads();

        // ---- recurrent dot: 256 MACs from registers + LDS ----
        float acc = 0.0f;
        const int hb = ks * 260;                       // HIDX(ks*256)
        #pragma unroll
        for (int j = 0; j < RCH; ++j) {
            const float4 hv = *reinterpret_cast<const float4*>(&hlds[hb + j * 4]);
            acc = fmaf(wreg[j].x, hv.x, acc);
            acc = fmaf(wreg[j].y, hv.y, acc);
            acc = fmaf(wreg[j].z, hv.z, acc);
            acc = fmaf(wreg[j].w, hv.w, acc);
        }
        #pragma unroll
        for (int j = 0; j < LCH; ++j) {
            const float4 wv = *reinterpret_cast<const float4*>(&wlds[(j * BTH + tid) * 4]);
            const float4 hv = *reinterpret_cast<const float4*>(&hlds[hb + (RCH + j) * 4]);
            acc = fmaf(wv.x, hv.x, acc);
            acc = fmaf(wv.y, hv.y, acc);
            acc = fmaf(wv.z, hv.z, acc);
            acc = fmaf(wv.w, hv.w, acc);
        }
        acc += __shfl_xor(acc, 1, 64);
        acc += __shfl_xor(acc, 2, 64);
        acc += __shfl_xor(acc, 4, 64);

        if (ks == 0) glds[g][ul] = acc + gxv + brow;
        __syncthreads();

        // ---- pointwise LSTM cell (16 units; wave 0) ----
        if (tid < UPW) {
            const float gi = sigmoidf_(glds[0][tid]);
            const float gf = sigmoidf_(glds[1][tid]);
            const float gg = tanhf(glds[2][tid]);
            const float go = sigmoidf_(glds[3][tid]);
            const float c  = gf * cst[tid] + gi * gg;
            cst[tid] = c;
            const float hv = go * tanhf(c);
            __hip_atomic_store(hs + (size_t)t * HH + w * UPW + tid, hv,
                               __ATOMIC_RELAXED, __HIP_MEMORY_SCOPE_AGENT);
        }
        __syncthreads();

        // ---- grid barrier: tree counters + replicated flags, all RELAXED ----
        if (tid == 0) {
            asm volatile("s_waitcnt vmcnt(0)" ::: "memory");  // drain wave-0 h stores
            unsigned* leaf = base + (w >> 4) * 64;
            const unsigned lo = __hip_atomic_fetch_add(leaf, 1u, __ATOMIC_RELAXED,
                                                       __HIP_MEMORY_SCOPE_AGENT);
            if (lo + 1 == 16u * (unsigned)(s + 1)) {
                unsigned* root = base + 8 * 64;
                const unsigned ro = __hip_atomic_fetch_add(root, 1u, __ATOMIC_RELAXED,
                                                           __HIP_MEMORY_SCOPE_AGENT);
                if (ro + 1 == 8u * (unsigned)(s + 1)) {
                    #pragma unroll
                    for (int f = 0; f < 8; ++f)
                        __hip_atomic_store(base + (9 + f) * 64, (unsigned)(s + 1),
                                           __ATOMIC_RELAXED, __HIP_MEMORY_SCOPE_AGENT);
                }
            }
            unsigned* fl = base + (9 + (w & 7)) * 64;
            while (__hip_atomic_load(fl, __ATOMIC_RELAXED, __HIP_MEMORY_SCOPE_AGENT)
                   < (unsigned)(s + 1)) {
                __builtin_amdgcn_s_sleep(2);
            }
            asm volatile("" ::: "memory");
        }
        __syncthreads();
    }
}

// out[t,v] = sum_j merged[t,j]*Wo[v,j] + bo[v],  merged = [hf | hb], K = 4096.
__global__ __launch_bounds__(256)
void out_gemm(const float* __restrict__ hsf, const float* __restrict__ hsb,
              const float* __restrict__ Wo, const float* __restrict__ bo,
              float* __restrict__ out)
{
    const int bn = blockIdx.x;
    const int bm = blockIdx.y;
    const int tid = threadIdx.x;
    const int tx = tid & 15, ty = tid >> 4;
    const int t0 = bm * 64, v0 = bn * 64;

    __shared__ float As[32][72];
    __shared__ float Bs[32][72];

    float acc[4][4] = {};

    const int rr = tid >> 2;
    const int kc = tid & 3;

    for (int kb = 0; kb < 2 * HH; kb += 32) {
        {
            const int k = kb + kc * 8;
            const float* asrc = (k < HH) ? (hsf + (size_t)(t0 + rr) * HH + k)
                                         : (hsb + (size_t)(t0 + rr) * HH + (k - HH));
            const float4 a0 = *reinterpret_cast<const float4*>(asrc);
            const float4 a1 = *reinterpret_cast<const float4*>(asrc + 4);
            const int kk = kc * 8;
            As[kk+0][rr]=a0.x; As[kk+1][rr]=a0.y; As[kk+2][rr]=a0.z; As[kk+3][rr]=a0.w;
            As[kk+4][rr]=a1.x; As[kk+5][rr]=a1.y; As[kk+6][rr]=a1.z; As[kk+7][rr]=a1.w;
            const float* bsrc = Wo + (size_t)(v0 + rr) * (2 * HH) + k;
            const float4 b0 = *reinterpret_cast<const float4*>(bsrc);
            const float4 b1 = *reinterpret_cast<const float4*>(bsrc + 4);
            Bs[kk+0][rr]=b0.x; Bs[kk+1][rr]=b0.y; Bs[kk+2][rr]=b0.z; Bs[kk+3][rr]=b0.w;
            Bs[kk+4][rr]=b1.x; Bs[kk+5][rr]=b1.y; Bs[kk+6][rr]=b1.z; Bs[kk+7][rr]=b1.w;
        }
        __syncthreads();
        #pragma unroll 8
        for (int kk = 0; kk < 32; ++kk) {
            const float4 av = *reinterpret_cast<const float4*>(&As[kk][ty * 4]);
            const float4 bv = *reinterpret_cast<const float4*>(&Bs[kk][tx * 4]);
            const float a[4] = {av.x, av.y, av.z, av.w};
            const float b[4] = {bv.x, bv.y, bv.z, bv.w};
            #pragma unroll
            for (int i2 = 0; i2 < 4; ++i2)
                #pragma unroll
                for (int j2 = 0; j2 < 4; ++j2)
                    acc[i2][j2] = fmaf(a[i2], b[j2], acc[i2][j2]);
        }
        __syncthreads();
    }
    #pragma unroll
    for (int i2 = 0; i2 < 4; ++i2) {
        const int t = t0 + ty * 4 + i2;
        #pragma unroll
        for (int j2 = 0; j2 < 4; ++j2) {
            const int v = v0 + tx * 4 + j2;
            out[(size_t)t * VV + v] = acc[i2][j2] + bo[v];
        }
    }
}

extern "C" void kernel_launch(void* const* d_in, const int* in_sizes, int n_in,
                              void* d_out, int out_size, void* d_ws, size_t ws_size,
                              hipStream_t stream)
{
    (void)in_sizes; (void)n_in; (void)out_size; (void)ws_size;

    const float* Wf  = (const float*)d_in[0];
    const float* bfv = (const float*)d_in[1];
    const float* Wb  = (const float*)d_in[2];
    const float* bbv = (const float*)d_in[3];
    const float* Wo  = (const float*)d_in[4];
    const float* bo  = (const float*)d_in[5];
    const int*   cid = (const int*)d_in[6];
    float* out = (float*)d_out;

    unsigned char* ws = (unsigned char*)d_ws;
    unsigned* bar = (unsigned*)ws;                         // 16 KiB barrier area
    float* hsf = (float*)(ws + 65536);                     // [T][H] fp32, 16 MiB
    float* hsb = hsf + (size_t)TT * HH;                    // [T][H] fp32, 16 MiB

    (void)hipMemsetAsync(bar, 0, 16384, stream);

    lstm_kernel<<<dim3(2 * NWGD), dim3(BTH), 0, stream>>>(Wf, bfv, Wb, bbv, cid,
                                                          hsf, hsb, bar);
    out_gemm<<<dim3(VV / 64, TT / 64), dim3(256), 0, stream>>>(hsf, hsb, Wo, bo, out);
}